// Round 6
// baseline (1420.413 us; speedup 1.0000x reference)
//
#include <hip/hip_runtime.h>

// Per-sample depthwise 7x7 cross-correlation, NHWC, SAME padding.
// inputs:  [B,H,W,C] fp32, kernels: [B,7,7,C] fp32, out: [B,H,W,C] fp32.
// out[b,y,x,c] = sum_{i,j} in[b, y+i-3, x+j-3, c] * ker[b,i,j,c]  (zero pad)
//
// R4 was LDS-pipe-bound (13 ds_read_b128 weight reads per row-pass per wave
// = ~158us/CU). R6 processes TWO input rows per weight pass with an 8-slot
// accumulator ring -> weight LDS traffic halved. Register budget kept in the
// 64-VGPR tier (acc 32 + taps 20 + quad 4) -> 8 waves/SIMD.

#define BB 32
#define HH 128
#define WW 128
#define CC 128
#define KH 7
#define KW 7

#define XPT 4                        // x outputs per thread
#define NTAP (XPT + KW - 1)          // 10 input columns per row per thread
#define XG 8                         // x-groups per block (1024 threads / 128 c)
#define SLABW (XG * XPT)             // 32 output columns per block
#define NXS (WW / SLABW)             // 4 x-slabs
#define YSPLIT 4
#define YROWS (HH / YSPLIT)          // 32 output rows per block
#define GRID (BB * NXS * YSPLIT)     // 512 blocks = 2 per CU
#define WSTRIDE 52                   // per-c weight stride (floats); 13*16B -> b128
                                     // quad-group (13c+k) mod 8 bijective: conflict-free
#define NPASS ((YROWS + KH - 1) / 2) // 19 double-row passes

__global__ __launch_bounds__(1024)
__attribute__((amdgpu_waves_per_eu(8)))
void crossconv_kernel(
    const float* __restrict__ in,
    const float* __restrict__ ker,
    float* __restrict__ out)
{
    __shared__ float lds_w[CC * WSTRIDE];   // 26624 B

    const int tid = threadIdx.x;
    const int c  = tid & (CC - 1);   // lanes contiguous in c -> coalesced
    // tid>>7 is constant within a 64-lane wave -> scalarize.
    const int xg = __builtin_amdgcn_readfirstlane(tid >> 7);   // 0..7

    // Bijective XCD swizzle (GRID=512, 64 blocks/XCD = 4 whole samples):
    // halo + weight sharing stays within one XCD's L2.
    const int bid = blockIdx.x;
    const int swz = (bid & 7) * (GRID / 8) + (bid >> 3);
    const int b  = swz >> 4;         // 16 blocks per sample
    const int xs = (swz >> 2) & 3;
    const int yh = swz & 3;
    const int x0 = xs * SLABW + xg * XPT;  // wave-uniform (scalar)
    const int y0 = yh * YROWS;

    // Stage this sample's weights into LDS, transposed to [c][f].
    {
        const float* kb = ker + ((size_t)b * KH * KW) * CC + c;
        for (int f = xg; f < KH * KW; f += XG)
            lds_w[c * WSTRIDE + f] = kb[f * CC];
    }
    __syncthreads();

    const float* ib = in  + ((size_t)b * HH * WW) * CC;
    float*       ob = out + ((size_t)b * HH * WW) * CC;
    const float* wp = &lds_w[c * WSTRIDE];

    // Taps cover columns x0-3 .. x0+XPT+2; wave-uniform edge test.
    const bool interior = (x0 >= 3) && (x0 + XPT + 2 < WW);

    auto load_taps = [&](float* t, int yi) {
        if (yi < 0 || yi >= HH) {
            #pragma unroll
            for (int j = 0; j < NTAP; ++j) t[j] = 0.0f;
            return;
        }
        const float* row = ib + (size_t)yi * WW * CC + c;  // per-lane part: c only
        if (interior) {
            #pragma unroll
            for (int j = 0; j < NTAP; ++j)
                t[j] = row[(x0 - 3 + j) * CC];             // scalar offsets
        } else {
            #pragma unroll
            for (int j = 0; j < NTAP; ++j) {
                const int xx = x0 - 3 + j;
                t[j] = (xx >= 0 && xx < WW) ? row[xx * CC] : 0.0f;
            }
        }
    };

    // 8-slot sliding ring: before a pass on rows (yi, yi+1), acc[s] holds the
    // partial for output row y = yi-3+s, s=0..7.
    float acc[KH + 1][XPT];
    #pragma unroll
    for (int s = 0; s < KH + 1; ++s)
        #pragma unroll
        for (int xo = 0; xo < XPT; ++xo) acc[s][xo] = 0.0f;

    const int yi0 = y0 - 3;

    #pragma unroll 1
    for (int p = 0; p < NPASS; ++p) {
        const int yi = yi0 + 2 * p;

        float t[NTAP], t2[NTAP];
        load_taps(t,  yi);       // row 1: feeds slot 6-i with kernel row i
        load_taps(t2, yi + 1);   // row 2: feeds slot 7-i

        // Keep the per-pass LDS weight reads in the loop (hoisting all 49
        // would blow the 64-VGPR tier and spill).
        asm volatile("" ::: "memory");

        #pragma unroll
        for (int k = 0; k < 12; ++k) {
            const float4 q = *(const float4*)(wp + k * 4);
            #pragma unroll
            for (int m = 0; m < 4; ++m) {
                const int f = k * 4 + m;
                const int i = f / KW, j = f % KW;
                const float wv = (&q.x)[m];
                #pragma unroll
                for (int xo = 0; xo < XPT; ++xo)
                    acc[6 - i][xo] = fmaf(wv, t[xo + j],  acc[6 - i][xo]);
                #pragma unroll
                for (int xo = 0; xo < XPT; ++xo)
                    acc[7 - i][xo] = fmaf(wv, t2[xo + j], acc[7 - i][xo]);
            }
        }
        {   // f = 48 (i=6, j=6) read as b128 (use .x only) -> conflict-free
            const float4 q = *(const float4*)(wp + 48);
            #pragma unroll
            for (int xo = 0; xo < XPT; ++xo)
                acc[0][xo] = fmaf(q.x, t[xo + 6],  acc[0][xo]);
            #pragma unroll
            for (int xo = 0; xo < XPT; ++xo)
                acc[1][xo] = fmaf(q.x, t2[xo + 6], acc[1][xo]);
        }

        // Outputs y = yi-3 (slot 0) and y = yi-2 (slot 1) are now complete.
        {
            const int y = yi - 3;
            if (y >= y0) {
                float* orow = ob + ((size_t)y * WW + x0) * CC + c;
                #pragma unroll
                for (int xo = 0; xo < XPT; ++xo)
                    orow[xo * CC] = acc[0][xo];
            }
            if (y + 1 >= y0) {   // upper bound guaranteed: y+1 <= y0+YROWS-1
                float* orow = ob + ((size_t)(y + 1) * WW + x0) * CC + c;
                #pragma unroll
                for (int xo = 0; xo < XPT; ++xo)
                    orow[xo * CC] = acc[1][xo];
            }
        }

        // Shift ring by 2, open two fresh slots.
        #pragma unroll
        for (int s = 0; s < KH - 1; ++s)
            #pragma unroll
            for (int xo = 0; xo < XPT; ++xo) acc[s][xo] = acc[s + 2][xo];
        #pragma unroll
        for (int xo = 0; xo < XPT; ++xo) {
            acc[KH - 1][xo] = 0.0f;
            acc[KH][xo]     = 0.0f;
        }
    }
}

extern "C" void kernel_launch(void* const* d_in, const int* in_sizes, int n_in,
                              void* d_out, int out_size, void* d_ws, size_t ws_size,
                              hipStream_t stream) {
    const float* in  = (const float*)d_in[0];
    const float* ker = (const float*)d_in[1];
    float*       out = (float*)d_out;

    crossconv_kernel<<<GRID, 1024, 0, stream>>>(in, ker, out);
}

// Round 8
// 143.403 us; speedup vs baseline: 9.9051x; 9.9051x over previous
//
#include <hip/hip_runtime.h>

// Per-sample depthwise 7x7 cross-correlation, NHWC, SAME padding.
// inputs:  [B,H,W,C] fp32, kernels: [B,7,7,C] fp32, out: [B,H,W,C] fp32.
// out[b,y,x,c] = sum_{i,j} in[b, y+i-3, x+j-3, c] * ker[b,i,j,c]  (zero pad)
//
// R8 = R7 with the cvt_pkrtz return-type fixed (bit_cast from __fp16x2).
// fp16 dot2 path (fp32 accumulate). Weights packed as half2 pairs in LDS
// ([c][28] uints = 7x16B rows, conflict-free b128 reads); per pass per row i:
// one ds_read_b128 gives the whole kernel row as 4 half2 pairs -> 4 v_dot2 per
// output x. Tap prefetch: packed current row (10 half2) + incoming fp32
// row (10 regs) fit the 64-VGPR tier -> 8 waves/SIMD. No occupancy attributes
// (waves_per_eu / launch_bounds minimums made the allocator spill in R2/R6).

#define BB 32
#define HH 128
#define WW 128
#define CC 128
#define KH 7
#define KW 7

#define XPT 4                        // x outputs per thread
#define NTAP (XPT + KW - 1)          // 10 input columns per row per thread
#define XG 8                         // x-groups per block (1024 threads / 128 c)
#define SLABW (XG * XPT)             // 32 output columns per block
#define NXS (WW / SLABW)             // 4 x-slabs
#define YSPLIT 4
#define YROWS (HH / YSPLIT)          // 32 output rows per block
#define GRID (BB * NXS * YSPLIT)     // 512 blocks = 2 per CU
#define WSLOTS 28                    // per-c packed-weight uints (7 rows x 4 pairs)
#define NPASS (YROWS + KH - 1)       // 38 single-row passes

typedef _Float16 half2_t __attribute__((ext_vector_type(2)));

static __device__ __forceinline__ half2_t pk(float a, float b) {
#if __has_builtin(__builtin_amdgcn_cvt_pkrtz)
    return __builtin_bit_cast(half2_t, __builtin_amdgcn_cvt_pkrtz(a, b));
#else
    half2_t r; r.x = (_Float16)a; r.y = (_Float16)b; return r;
#endif
}

static __device__ __forceinline__ float dot2f(unsigned w, half2_t t, float c) {
#if __has_builtin(__builtin_amdgcn_fdot2)
    return __builtin_amdgcn_fdot2(__builtin_bit_cast(half2_t, w), t, c, false);
#else
    half2_t wv = __builtin_bit_cast(half2_t, w);
    return fmaf((float)wv.x, (float)t.x, fmaf((float)wv.y, (float)t.y, c));
#endif
}

__global__ __launch_bounds__(1024) void crossconv_kernel(
    const float* __restrict__ in,
    const float* __restrict__ ker,
    float* __restrict__ out)
{
    __shared__ unsigned lds_w[CC * WSLOTS];   // 14336 B

    const int tid = threadIdx.x;
    const int c  = tid & (CC - 1);   // lanes contiguous in c -> coalesced
    const int xg = __builtin_amdgcn_readfirstlane(tid >> 7);   // 0..7, wave-uniform

    // Bijective XCD swizzle (GRID=512, 64 blocks/XCD = 4 whole samples).
    const int bid = blockIdx.x;
    const int swz = (bid & 7) * (GRID / 8) + (bid >> 3);
    const int b  = swz >> 4;         // 16 blocks per sample
    const int xs = (swz >> 2) & 3;
    const int yh = swz & 3;
    const int x0 = xs * SLABW + xg * XPT;  // wave-uniform (scalar)
    const int y0 = yh * YROWS;

    // Stage packed weights into LDS: slot s (0..27) -> row i=s>>2, pair q=s&3.
    // q<3: (w[i][2q], w[i][2q+1]); q==3: (w[i][6], 0).
    {
        const float* kb = ker + ((size_t)b * KH * KW) * CC + c;
        for (int s = xg; s < WSLOTS; s += XG) {
            const int i = s >> 2, q = s & 3;
            half2_t pr;
            if (q < 3) {
                const int f0 = i * KW + 2 * q;
                pr = pk(kb[f0 * CC], kb[(f0 + 1) * CC]);
            } else {
                pr = pk(kb[(i * KW + 6) * CC], 0.0f);
            }
            lds_w[c * WSLOTS + s] = __builtin_bit_cast(unsigned, pr);
        }
    }
    __syncthreads();

    const float* ib = in  + ((size_t)b * HH * WW) * CC;
    float*       ob = out + ((size_t)b * HH * WW) * CC;
    const unsigned* wlds = &lds_w[c * WSLOTS];

    const bool interior = (x0 >= 3) && (x0 + XPT + 2 < WW);

    auto load_taps = [&](float* t, int yi) {
        if (yi < 0 || yi >= HH) {
            #pragma unroll
            for (int j = 0; j < NTAP; ++j) t[j] = 0.0f;
            return;
        }
        const float* row = ib + (size_t)yi * WW * CC + c;  // per-lane part: c only
        if (interior) {
            #pragma unroll
            for (int j = 0; j < NTAP; ++j)
                t[j] = row[(x0 - 3 + j) * CC];             // scalar offsets
        } else {
            #pragma unroll
            for (int j = 0; j < NTAP; ++j) {
                const int xx = x0 - 3 + j;
                t[j] = (xx >= 0 && xx < WW) ? row[xx * CC] : 0.0f;
            }
        }
    };

    // Sliding ring: acc[s][xo] partial for output row y = yi-3+s.
    float acc[KH][XPT];
    #pragma unroll
    for (int s = 0; s < KH; ++s)
        #pragma unroll
        for (int xo = 0; xo < XPT; ++xo) acc[s][xo] = 0.0f;

    const int yi0 = y0 - 3;

    // Packed taps for the CURRENT pass row:
    // e[k] = (t[2k], t[2k+1])  k=0..4 ; o[k] = (t[2k+1], t[2k+2]) k=0..3,
    // o[4] = (t[9], 0).  Even xo reads e[xo/2+q], odd xo reads o[(xo-1)/2+q].
    float t[NTAP];
    half2_t e[5], o[5];
    load_taps(t, yi0);
    #pragma unroll
    for (int k = 0; k < 5; ++k) e[k] = pk(t[2 * k], t[2 * k + 1]);
    #pragma unroll
    for (int k = 0; k < 4; ++k) o[k] = pk(t[2 * k + 1], t[2 * k + 2]);
    o[4] = pk(t[9], 0.0f);

    #pragma unroll 1
    for (int p = 0; p < NPASS; ++p) {
        const int yi = yi0 + p;

        // Issue next row's tap loads; the dot pass below hides the latency.
        load_taps(t, (p + 1 < NPASS) ? (yi + 1) : -1);

        // Keep per-pass LDS weight reads in the loop (hoisting 28 pairs would
        // blow the 64-VGPR tier and spill).
        asm volatile("" ::: "memory");

        #pragma unroll
        for (int i = 0; i < KH; ++i) {
            const uint4 wq = *(const uint4*)(wlds + i * 4);   // kernel row i
            const int s = 6 - i;
            #pragma unroll
            for (int xo = 0; xo < XPT; ++xo) {
                float a = acc[s][xo];
                if ((xo & 1) == 0) {
                    const int k0 = xo >> 1;
                    a = dot2f(wq.x, e[k0],     a);
                    a = dot2f(wq.y, e[k0 + 1], a);
                    a = dot2f(wq.z, e[k0 + 2], a);
                    a = dot2f(wq.w, e[k0 + 3], a);
                } else {
                    const int k0 = (xo - 1) >> 1;
                    a = dot2f(wq.x, o[k0],     a);
                    a = dot2f(wq.y, o[k0 + 1], a);
                    a = dot2f(wq.z, o[k0 + 2], a);
                    a = dot2f(wq.w, o[k0 + 3], a);
                }
                acc[s][xo] = a;
            }
        }

        const int y = yi - 3;
        if (y >= y0) {
            float* orow = ob + ((size_t)y * WW + x0) * CC + c;
            #pragma unroll
            for (int xo = 0; xo < XPT; ++xo)
                orow[xo * CC] = acc[0][xo];
        }

        // Shift ring, open fresh top slot.
        #pragma unroll
        for (int s = 0; s < KH - 1; ++s)
            #pragma unroll
            for (int xo = 0; xo < XPT; ++xo) acc[s][xo] = acc[s + 1][xo];
        #pragma unroll
        for (int xo = 0; xo < XPT; ++xo) acc[KH - 1][xo] = 0.0f;

        // Convert the prefetched row into the packed operands for next pass.
        #pragma unroll
        for (int k = 0; k < 5; ++k) e[k] = pk(t[2 * k], t[2 * k + 1]);
        #pragma unroll
        for (int k = 0; k < 4; ++k) o[k] = pk(t[2 * k + 1], t[2 * k + 2]);
        o[4] = pk(t[9], 0.0f);
    }
}

extern "C" void kernel_launch(void* const* d_in, const int* in_sizes, int n_in,
                              void* d_out, int out_size, void* d_ws, size_t ws_size,
                              hipStream_t stream) {
    const float* in  = (const float*)d_in[0];
    const float* ker = (const float*)d_in[1];
    float*       out = (float*)d_out;

    crossconv_kernel<<<GRID, 1024, 0, stream>>>(in, ker, out);
}